// Round 1
// baseline (427.726 us; speedup 1.0000x reference)
//
#include <hip/hip_runtime.h>

// CRF log-likelihood, B=1024, S=512, TAGSET=64, NUM_TAGS=66.
// One wave (64 lanes) per batch element; lane j holds alpha_j and expT[:,j].
// Hot loop: readlane-broadcast matvec (no LDS, no barriers).

#define B_N   1024
#define S_N   512
#define TG    64
#define NT    66
#define STARTT 64
#define STOPT  65
#define PD    4     // emission prefetch depth (covers ~HBM latency at 1 wave/SIMD)

__device__ __forceinline__ float bcast(float v, int l) {
    return __uint_as_float(__builtin_amdgcn_readlane(__float_as_uint(v), l));
}

__global__ __launch_bounds__(64, 1) void crf_fwd(
    const float* __restrict__ em,    // [B,S,64]
    const int*   __restrict__ tags,  // [B,S]
    const float* __restrict__ T,     // [66,66]
    float*       __restrict__ out)   // [B]
{
    const int b    = blockIdx.x;
    const int lane = threadIdx.x;  // 0..63

    __shared__ int s_tags[S_N];

    // Stage this batch's tags into LDS (coalesced).
    const int* tb = tags + b * S_N;
#pragma unroll
    for (int k = 0; k < S_N / TG; ++k)
        s_tags[k * TG + lane] = tb[k * TG + lane];

    // Per-lane column of exp(Tsub): Tcol[i] = exp(T[i, lane]). Stays in VGPRs.
    float Tcol[TG];
#pragma unroll
    for (int i = 0; i < TG; ++i)
        Tcol[i] = __expf(T[i * NT + lane]);
    const float Tstart = T[STARTT * NT + lane];   // T[START, lane]
    const float Tend   = T[lane * NT + STOPT];    // T[lane, STOP]

    const float* emb = em + (size_t)b * (S_N * TG);
    float alpha = emb[lane] + Tstart;             // log_alpha0

    __syncthreads();

    // Software prefetch pipeline for emissions, depth PD.
    float em_pre[PD];
#pragma unroll
    for (int d = 0; d < PD; ++d)
        em_pre[d] = emb[(1 + d) * TG + lane];

    for (int t = 1; t < S_N; ++t) {
        const float em_cur = em_pre[0];
        em_pre[0] = em_pre[1];
        em_pre[1] = em_pre[2];
        em_pre[2] = em_pre[3];
        const int tp = t + PD;
        em_pre[PD - 1] = (tp < S_N) ? emb[tp * TG + lane] : 0.0f;

        // Wave-uniform tag -> scalar branch.
        const int tag = __builtin_amdgcn_readfirstlane(s_tags[t]);
        if (tag != 0) {
            // m = max_j alpha_j (butterfly over 64 lanes)
            float m = alpha;
#pragma unroll
            for (int d = 1; d < TG; d <<= 1)
                m = fmaxf(m, __shfl_xor(m, d));
            const float E = __expf(alpha - m);

            // s_j = sum_i E_i * expT[i][j]; E_i broadcast via v_readlane -> SGPR,
            // consumed by v_fmac_f32 (sgpr,vgpr,vgpr). 4 accumulators for ILP.
            float s0 = 0.f, s1 = 0.f, s2 = 0.f, s3 = 0.f;
#pragma unroll
            for (int i = 0; i < TG; i += 4) {
                s0 = fmaf(bcast(E, i + 0), Tcol[i + 0], s0);
                s1 = fmaf(bcast(E, i + 1), Tcol[i + 1], s1);
                s2 = fmaf(bcast(E, i + 2), Tcol[i + 2], s2);
                s3 = fmaf(bcast(E, i + 3), Tcol[i + 3], s3);
            }
            const float ssum = (s0 + s1) + (s2 + s3);
            // score = ln(ssum) + m + em_t[j]; then +Tend (unconditional in ref)
            alpha = __logf(ssum) + m + em_cur + Tend;
        } else {
            // masked step: la = alpha; then +Tend
            alpha += Tend;
        }
    }

    // log_z = logsumexp_j(alpha)
    float m = alpha;
#pragma unroll
    for (int d = 1; d < TG; d <<= 1)
        m = fmaxf(m, __shfl_xor(m, d));
    float ez = __expf(alpha - m);
#pragma unroll
    for (int d = 1; d < TG; d <<= 1)
        ez += __shfl_xor(ez, d);
    const float log_z = __logf(ez) + m;

    // Numerator: gold-path score. 8 timesteps per lane.
    float num = 0.0f;
    int   cnt = 0;
#pragma unroll
    for (int k = 0; k < S_N / TG; ++k) {
        const int t   = k * TG + lane;
        const int tag = s_tags[t];
        const int mt  = (tag != 0) ? 1 : 0;
        cnt += mt;
        const float emg = emb[t * TG + tag];   // em gather (L2/L3-resident)
        if (t == 0) {
            num += T[STARTT * NT + tag] + emg * (float)mt;
        } else {
            const int prev = s_tags[t - 1];
            num += (emg + T[prev * NT + tag]) * (float)mt;
        }
    }
#pragma unroll
    for (int d = 1; d < TG; d <<= 1) {
        num += __shfl_xor(num, d);
        cnt += __shfl_xor(cnt, d);
    }
    int last_idx = cnt - 1;
    if (last_idx < 0) last_idx = 0;
    const int last_tag = s_tags[last_idx];
    num += T[last_tag * NT + STOPT];

    if (lane == 0) out[b] = num - log_z;
}

extern "C" void kernel_launch(void* const* d_in, const int* in_sizes, int n_in,
                              void* d_out, int out_size, void* d_ws, size_t ws_size,
                              hipStream_t stream) {
    const float* em   = (const float*)d_in[0];
    const int*   tags = (const int*)d_in[1];
    const float* T    = (const float*)d_in[2];
    float* out = (float*)d_out;
    crf_fwd<<<dim3(B_N), dim3(TG), 0, stream>>>(em, tags, T, out);
}

// Round 2
// 389.971 us; speedup vs baseline: 1.0968x; 1.0968x over previous
//
#include <hip/hip_runtime.h>

// CRF log-likelihood, B=1024, S=512, TAGSET=64, NUM_TAGS=66.
// One wave per batch element; lane j holds alpha_j and expT[:,j] (f16 pairs).
// Hot loop: readlane-broadcast f16 dot2 matvec; no butterfly (m = alpha[lane0]);
// tag+emission register prefetch pipelines keep LDS/HBM latency off the
// critical path (1 wave/SIMD -> zero TLP, pure ILP design).

#define B_N   1024
#define S_N   512
#define TG    64
#define NT    66
#define STARTT 64
#define STOPT  65
#define PD    4     // emission prefetch depth
#define TPD   3     // tag prefetch depth

typedef __attribute__((ext_vector_type(2))) _Float16 half2_t;

__device__ __forceinline__ float bcastf(float v, int l) {
    return __uint_as_float(__builtin_amdgcn_readlane(__float_as_uint(v), l));
}
__device__ __forceinline__ int bcasti(int v, int l) {
    return __builtin_amdgcn_readlane(v, l);
}

__global__ __launch_bounds__(64, 1) void crf_fwd(
    const float* __restrict__ em,    // [B,S,64]
    const int*   __restrict__ tags,  // [B,S]
    const float* __restrict__ T,     // [66,66]
    float*       __restrict__ out)   // [B]
{
    const int b    = blockIdx.x;
    const int lane = threadIdx.x;  // 0..63

    __shared__ int s_tags[S_N];

    // Stage this batch's tags into LDS (coalesced).
    const int* tb = tags + b * S_N;
#pragma unroll
    for (int k = 0; k < S_N / TG; ++k)
        s_tags[k * TG + lane] = tb[k * TG + lane];

#if __has_builtin(__builtin_amdgcn_fdot2)
    // Per-lane column of exp(Tsub) as f16 pairs: Th[k] = (expT[2k][lane], expT[2k+1][lane]).
    // T in [-0.1,0.1] -> expT in [0.9,1.1]; f16 relerr 5e-4, irrelevant vs 1e5 threshold.
    half2_t Th[TG / 2];
#pragma unroll
    for (int k = 0; k < TG / 2; ++k) {
        const float a = __expf(T[(2 * k + 0) * NT + lane]);
        const float c = __expf(T[(2 * k + 1) * NT + lane]);
        Th[k] = half2_t{(_Float16)a, (_Float16)c};
    }
#else
    float Tcol[TG];
#pragma unroll
    for (int i = 0; i < TG; ++i)
        Tcol[i] = __expf(T[i * NT + lane]);
#endif
    const float Tstart = T[STARTT * NT + lane];   // T[START, lane]
    const float Tend   = T[lane * NT + STOPT];    // T[lane, STOP] (= -10000 here)

    const float* emb = em + (size_t)b * (S_N * TG);
    float alpha = emb[lane] + Tstart;             // log_alpha0

    __syncthreads();

    // Register prefetch pipelines (depth PD emissions, TPD tags).
    float em_pre0 = emb[1 * TG + lane];
    float em_pre1 = emb[2 * TG + lane];
    float em_pre2 = emb[3 * TG + lane];
    float em_pre3 = emb[4 * TG + lane];
    int tag_pre0 = s_tags[1];
    int tag_pre1 = s_tags[2];
    int tag_pre2 = s_tags[3];

    for (int t = 1; t < S_N; ++t) {
        const float em_cur = em_pre0;
        em_pre0 = em_pre1; em_pre1 = em_pre2; em_pre2 = em_pre3;
        int tp = t + PD; tp = (tp < S_N - 1) ? tp : (S_N - 1);
        em_pre3 = emb[tp * TG + lane];

        const int tag = __builtin_amdgcn_readfirstlane(tag_pre0);
        tag_pre0 = tag_pre1; tag_pre1 = tag_pre2;
        int tn = t + TPD; tn = (tn < S_N - 1) ? tn : (S_N - 1);
        tag_pre2 = s_tags[tn];

        if (tag != 0) {
            // m: any wave-uniform value is mathematically exact; lane0's alpha
            // keeps |alpha - m| <= ~12 (emission spread bound). Extra -2 keeps
            // exp() under f16 max (6.6e4) on the high side.
            const float m = bcastf(alpha, 0);
            const float E = __expf(alpha - m - 2.0f);

#if __has_builtin(__builtin_amdgcn_fdot2)
            // Pack neighbor-lane pair (E_2k, E_2k+1) into f16x2 (same value in
            // both lanes of the pair), broadcast packed pair via one readlane.
            const float En = __shfl_xor(E, 1);
            const float lo = (lane & 1) ? En : E;
            const float hi = (lane & 1) ? E  : En;
            const half2_t ep = half2_t{(_Float16)lo, (_Float16)hi};
            const int epi = __builtin_bit_cast(int, ep);

            float s0 = 0.f, s1 = 0.f, s2 = 0.f, s3 = 0.f;
#pragma unroll
            for (int k = 0; k < TG / 2; k += 4) {
                s0 = __builtin_amdgcn_fdot2(__builtin_bit_cast(half2_t, bcasti(epi, 2 * (k + 0))), Th[k + 0], s0, false);
                s1 = __builtin_amdgcn_fdot2(__builtin_bit_cast(half2_t, bcasti(epi, 2 * (k + 1))), Th[k + 1], s1, false);
                s2 = __builtin_amdgcn_fdot2(__builtin_bit_cast(half2_t, bcasti(epi, 2 * (k + 2))), Th[k + 2], s2, false);
                s3 = __builtin_amdgcn_fdot2(__builtin_bit_cast(half2_t, bcasti(epi, 2 * (k + 3))), Th[k + 3], s3, false);
            }
#else
            float s0 = 0.f, s1 = 0.f, s2 = 0.f, s3 = 0.f;
#pragma unroll
            for (int i = 0; i < TG; i += 4) {
                s0 = fmaf(bcastf(E, i + 0), Tcol[i + 0], s0);
                s1 = fmaf(bcastf(E, i + 1), Tcol[i + 1], s1);
                s2 = fmaf(bcastf(E, i + 2), Tcol[i + 2], s2);
                s3 = fmaf(bcastf(E, i + 3), Tcol[i + 3], s3);
            }
#endif
            const float ssum = (s0 + s1) + (s2 + s3);
            alpha = __logf(ssum) + (m + 2.0f) + em_cur + Tend;
        } else {
            alpha += Tend;
        }
    }

    // log_z = logsumexp_j(alpha) — once; butterfly cost irrelevant here.
    float mz = alpha;
#pragma unroll
    for (int d = 1; d < TG; d <<= 1)
        mz = fmaxf(mz, __shfl_xor(mz, d));
    float ez = __expf(alpha - mz);
#pragma unroll
    for (int d = 1; d < TG; d <<= 1)
        ez += __shfl_xor(ez, d);
    const float log_z = __logf(ez) + mz;

    // Numerator: gold-path score. 8 timesteps per lane.
    float num = 0.0f;
    int   cnt = 0;
#pragma unroll
    for (int k = 0; k < S_N / TG; ++k) {
        const int t   = k * TG + lane;
        const int tag = s_tags[t];
        const int mt  = (tag != 0) ? 1 : 0;
        cnt += mt;
        const float emg = emb[t * TG + tag];
        if (t == 0) {
            num += T[STARTT * NT + tag] + emg * (float)mt;
        } else {
            const int prev = s_tags[t - 1];
            num += (emg + T[prev * NT + tag]) * (float)mt;
        }
    }
#pragma unroll
    for (int d = 1; d < TG; d <<= 1) {
        num += __shfl_xor(num, d);
        cnt += __shfl_xor(cnt, d);
    }
    int last_idx = cnt - 1;
    if (last_idx < 0) last_idx = 0;
    const int last_tag = s_tags[last_idx];
    num += T[last_tag * NT + STOPT];

    if (lane == 0) out[b] = num - log_z;
}

extern "C" void kernel_launch(void* const* d_in, const int* in_sizes, int n_in,
                              void* d_out, int out_size, void* d_ws, size_t ws_size,
                              hipStream_t stream) {
    const float* em   = (const float*)d_in[0];
    const int*   tags = (const int*)d_in[1];
    const float* T    = (const float*)d_in[2];
    float* out = (float*)d_out;
    crf_fwd<<<dim3(B_N), dim3(TG), 0, stream>>>(em, tags, T, out);
}

// Round 3
// 373.635 us; speedup vs baseline: 1.1448x; 1.0437x over previous
//
#include <hip/hip_runtime.h>

// CRF log-likelihood, B=1024, S=512, TAGSET=64, NUM_TAGS=66.
// One wave per batch element; lane j holds alpha_j and expT[:,j].
// R3: expT column kept in 16 named float4s (guaranteed VGPRs — R1/R2 had the
// per-thread array lowered to scratch: VGPR_Count 40, WRITE_SIZE 40MB, ~740
// cy/step of scratch-reload latency). Hot loop: readlane-broadcast f32 matvec,
// no ds ops on the alpha critical chain; m = alpha[lane0] (wave-uniform shift
// is mathematically exact; spread bounded ~12 so exp stays in f32 range).

#define B_N   1024
#define S_N   512
#define TG    64
#define NT    66
#define STARTT 64
#define STOPT  65
#define PD    4     // emission prefetch depth
#define TPD   3     // tag prefetch depth

__device__ __forceinline__ float bcastf(float v, int l) {
    return __uint_as_float(__builtin_amdgcn_readlane(__float_as_uint(v), l));
}

#define Q_LIST(M) M(0) M(1) M(2) M(3) M(4) M(5) M(6) M(7) \
                  M(8) M(9) M(10) M(11) M(12) M(13) M(14) M(15)

__global__ __launch_bounds__(64, 1) void crf_fwd(
    const float* __restrict__ em,    // [B,S,64]
    const int*   __restrict__ tags,  // [B,S]
    const float* __restrict__ T,     // [66,66]
    float*       __restrict__ out)   // [B]
{
    const int b    = blockIdx.x;
    const int lane = threadIdx.x;  // 0..63

    __shared__ int s_tags[S_N];

    // Stage this batch's tags into LDS (coalesced).
    const int* tb = tags + b * S_N;
#pragma unroll
    for (int k = 0; k < S_N / TG; ++k)
        s_tags[k * TG + lane] = tb[k * TG + lane];

    // expT column for this lane: c{q}.{x,y,z,w} = exp(T[4q+c][lane]).
    // Named float4 fields -> SROA-promoted -> VGPRs (no scratch).
    const float* Tl = T + lane;
#define INITQ(q) \
    float4 c##q; \
    c##q.x = __expf(Tl[(4*q + 0) * NT]); \
    c##q.y = __expf(Tl[(4*q + 1) * NT]); \
    c##q.z = __expf(Tl[(4*q + 2) * NT]); \
    c##q.w = __expf(Tl[(4*q + 3) * NT]);
    Q_LIST(INITQ)
#undef INITQ

    const float Tstart = T[STARTT * NT + lane];   // T[START, lane]
    const float Tend   = T[lane * NT + STOPT];    // T[lane, STOP]

    const float* emb = em + (size_t)b * (S_N * TG);
    float alpha = emb[lane] + Tstart;             // log_alpha0

    __syncthreads();

    // Register prefetch pipelines (scalars only — no arrays anywhere).
    float em_pre0 = emb[1 * TG + lane];
    float em_pre1 = emb[2 * TG + lane];
    float em_pre2 = emb[3 * TG + lane];
    float em_pre3 = emb[4 * TG + lane];
    int tag_pre0 = s_tags[1];
    int tag_pre1 = s_tags[2];
    int tag_pre2 = s_tags[3];

    for (int t = 1; t < S_N; ++t) {
        const float em_cur = em_pre0;
        em_pre0 = em_pre1; em_pre1 = em_pre2; em_pre2 = em_pre3;
        int tp = t + PD; tp = (tp < S_N - 1) ? tp : (S_N - 1);
        em_pre3 = emb[tp * TG + lane];

        const int tag = __builtin_amdgcn_readfirstlane(tag_pre0);
        tag_pre0 = tag_pre1; tag_pre1 = tag_pre2;
        int tn = t + TPD; tn = (tn < S_N - 1) ? tn : (S_N - 1);
        tag_pre2 = s_tags[tn];

        if (tag != 0) {
            // Wave-uniform shift: exact for logsumexp; lane0's alpha keeps
            // |alpha - m| <= ~12 (emission spread bound), exp in f32 range.
            const float m = bcastf(alpha, 0);
            const float E = __expf(alpha - m);

            // s_j = sum_i E_i * expT[i][j]; E_i broadcast via v_readlane
            // (immediate lane -> SGPR feeding v_fmac). 4 chains for ILP.
            float s0 = 0.f, s1 = 0.f, s2 = 0.f, s3 = 0.f;
#define MATQ(q) \
            s0 = fmaf(bcastf(E, 4*q + 0), c##q.x, s0); \
            s1 = fmaf(bcastf(E, 4*q + 1), c##q.y, s1); \
            s2 = fmaf(bcastf(E, 4*q + 2), c##q.z, s2); \
            s3 = fmaf(bcastf(E, 4*q + 3), c##q.w, s3);
            Q_LIST(MATQ)
#undef MATQ
            const float ssum = (s0 + s1) + (s2 + s3);
            alpha = __logf(ssum) + m + em_cur + Tend;
        } else {
            alpha += Tend;
        }
    }

    // log_z = logsumexp_j(alpha) — once; butterfly cost irrelevant here.
    float mz = alpha;
#pragma unroll
    for (int d = 1; d < TG; d <<= 1)
        mz = fmaxf(mz, __shfl_xor(mz, d));
    float ez = __expf(alpha - mz);
#pragma unroll
    for (int d = 1; d < TG; d <<= 1)
        ez += __shfl_xor(ez, d);
    const float log_z = __logf(ez) + mz;

    // Numerator: gold-path score. 8 timesteps per lane.
    float num = 0.0f;
    int   cnt = 0;
#pragma unroll
    for (int k = 0; k < S_N / TG; ++k) {
        const int t   = k * TG + lane;
        const int tag = s_tags[t];
        const int mt  = (tag != 0) ? 1 : 0;
        cnt += mt;
        const float emg = emb[t * TG + tag];
        if (t == 0) {
            num += T[STARTT * NT + tag] + emg * (float)mt;
        } else {
            const int prev = s_tags[t - 1];
            num += (emg + T[prev * NT + tag]) * (float)mt;
        }
    }
#pragma unroll
    for (int d = 1; d < TG; d <<= 1) {
        num += __shfl_xor(num, d);
        cnt += __shfl_xor(cnt, d);
    }
    int last_idx = cnt - 1;
    if (last_idx < 0) last_idx = 0;
    const int last_tag = s_tags[last_idx];
    num += T[last_tag * NT + STOPT];

    if (lane == 0) out[b] = num - log_z;
}

extern "C" void kernel_launch(void* const* d_in, const int* in_sizes, int n_in,
                              void* d_out, int out_size, void* d_ws, size_t ws_size,
                              hipStream_t stream) {
    const float* em   = (const float*)d_in[0];
    const int*   tags = (const int*)d_in[1];
    const float* T    = (const float*)d_in[2];
    float* out = (float*)d_out;
    crf_fwd<<<dim3(B_N), dim3(TG), 0, stream>>>(em, tags, T, out);
}

// Round 4
// 371.859 us; speedup vs baseline: 1.1502x; 1.0048x over previous
//
#include <hip/hip_runtime.h>

// CRF log-likelihood, B=1024, S=512, TAGSET=64, NUM_TAGS=66.
// One wave per batch element; lane j holds alpha_j and expT[:,j].
// R4: the 64 expT column values are PINNED into VGPRs via empty asm volatile
// ("+v") — R1-R3 all showed VGPR_Count=44 + WRITE_SIZE~41MB, i.e. the
// compiler demoted the column to scratch/reload regardless of array vs named
// float4 form; at 1 wave/SIMD every reload is exposed latency (~700 cy/step).
// Hot loop: readlane-broadcast f32 matvec, m = alpha[lane0] (wave-uniform
// shift is mathematically exact; spread bounded ~12 so exp stays in range).

#define B_N   1024
#define S_N   512
#define TG    64
#define NT    66
#define STARTT 64
#define STOPT  65
#define PD    4     // emission prefetch depth
#define TPD   3     // tag prefetch depth

__device__ __forceinline__ float bcastf(float v, int l) {
    return __uint_as_float(__builtin_amdgcn_readlane(__float_as_uint(v), l));
}

#define PIN(x) asm volatile("" : "+v"(x))

// 16 groups of 4 explicit indices (preprocessor can't do arithmetic on ##).
#define GROUPS(M) \
  M(0,1,2,3)     M(4,5,6,7)     M(8,9,10,11)   M(12,13,14,15) \
  M(16,17,18,19) M(20,21,22,23) M(24,25,26,27) M(28,29,30,31) \
  M(32,33,34,35) M(36,37,38,39) M(40,41,42,43) M(44,45,46,47) \
  M(48,49,50,51) M(52,53,54,55) M(56,57,58,59) M(60,61,62,63)

__global__ __launch_bounds__(64, 1) void crf_fwd(
    const float* __restrict__ em,    // [B,S,64]
    const int*   __restrict__ tags,  // [B,S]
    const float* __restrict__ T,     // [66,66]
    float*       __restrict__ out)   // [B]
{
    const int b    = blockIdx.x;
    const int lane = threadIdx.x;  // 0..63

    __shared__ int s_tags[S_N];

    // Stage this batch's tags into LDS (coalesced).
    const int* tb = tags + b * S_N;
#pragma unroll
    for (int k = 0; k < S_N / TG; ++k)
        s_tags[k * TG + lane] = tb[k * TG + lane];

    // expT column for this lane: e{i} = exp(T[i][lane]), i = 0..63.
    const float* Tl = T + lane;
#define INITG(a,b_,c_,d_) \
    float e##a  = __expf(Tl[a  * NT]); \
    float e##b_ = __expf(Tl[b_ * NT]); \
    float e##c_ = __expf(Tl[c_ * NT]); \
    float e##d_ = __expf(Tl[d_ * NT]);
    GROUPS(INITG)
#undef INITG
    // Pin every value into a VGPR: empty asm output can't be rematerialized
    // or sunk into the loop -> guaranteed register residency.
#define PING(a,b_,c_,d_) PIN(e##a); PIN(e##b_); PIN(e##c_); PIN(e##d_);
    GROUPS(PING)
#undef PING

    const float Tstart = T[STARTT * NT + lane];   // T[START, lane]
    const float Tend   = T[lane * NT + STOPT];    // T[lane, STOP]

    const float* emb = em + (size_t)b * (S_N * TG);
    float alpha = emb[lane] + Tstart;             // log_alpha0

    __syncthreads();

    // Register prefetch pipelines (scalars only).
    float em_pre0 = emb[1 * TG + lane];
    float em_pre1 = emb[2 * TG + lane];
    float em_pre2 = emb[3 * TG + lane];
    float em_pre3 = emb[4 * TG + lane];
    int tag_pre0 = s_tags[1];
    int tag_pre1 = s_tags[2];
    int tag_pre2 = s_tags[3];

    for (int t = 1; t < S_N; ++t) {
        const float em_cur = em_pre0;
        em_pre0 = em_pre1; em_pre1 = em_pre2; em_pre2 = em_pre3;
        int tp = t + PD; tp = (tp < S_N - 1) ? tp : (S_N - 1);
        em_pre3 = emb[tp * TG + lane];

        const int tag = __builtin_amdgcn_readfirstlane(tag_pre0);
        tag_pre0 = tag_pre1; tag_pre1 = tag_pre2;
        int tn = t + TPD; tn = (tn < S_N - 1) ? tn : (S_N - 1);
        tag_pre2 = s_tags[tn];

        if (tag != 0) {
            // Wave-uniform shift: exact for logsumexp; lane0's alpha keeps
            // |alpha - m| <= ~12 (emission spread bound).
            const float m = bcastf(alpha, 0);
            const float E = __expf(alpha - m);

            // s_j = sum_i E_i * expT[i][j]; E_i broadcast via v_readlane
            // (immediate lane -> SGPR feeding v_fmac). 4 chains for ILP.
            float s0 = 0.f, s1 = 0.f, s2 = 0.f, s3 = 0.f;
#define FMAG(a,b_,c_,d_) \
            s0 = fmaf(bcastf(E, a ), e##a , s0); \
            s1 = fmaf(bcastf(E, b_), e##b_, s1); \
            s2 = fmaf(bcastf(E, c_), e##c_, s2); \
            s3 = fmaf(bcastf(E, d_), e##d_, s3);
            GROUPS(FMAG)
#undef FMAG
            const float ssum = (s0 + s1) + (s2 + s3);
            alpha = __logf(ssum) + m + em_cur + Tend;
        } else {
            alpha += Tend;
        }
    }

    // log_z = logsumexp_j(alpha) — once; butterfly cost irrelevant here.
    float mz = alpha;
#pragma unroll
    for (int d = 1; d < TG; d <<= 1)
        mz = fmaxf(mz, __shfl_xor(mz, d));
    float ez = __expf(alpha - mz);
#pragma unroll
    for (int d = 1; d < TG; d <<= 1)
        ez += __shfl_xor(ez, d);
    const float log_z = __logf(ez) + mz;

    // Numerator: gold-path score. 8 timesteps per lane.
    float num = 0.0f;
    int   cnt = 0;
#pragma unroll
    for (int k = 0; k < S_N / TG; ++k) {
        const int t   = k * TG + lane;
        const int tag = s_tags[t];
        const int mt  = (tag != 0) ? 1 : 0;
        cnt += mt;
        const float emg = emb[t * TG + tag];
        if (t == 0) {
            num += T[STARTT * NT + tag] + emg * (float)mt;
        } else {
            const int prev = s_tags[t - 1];
            num += (emg + T[prev * NT + tag]) * (float)mt;
        }
    }
#pragma unroll
    for (int d = 1; d < TG; d <<= 1) {
        num += __shfl_xor(num, d);
        cnt += __shfl_xor(cnt, d);
    }
    int last_idx = cnt - 1;
    if (last_idx < 0) last_idx = 0;
    const int last_tag = s_tags[last_idx];
    num += T[last_tag * NT + STOPT];

    if (lane == 0) out[b] = num - log_z;
}

extern "C" void kernel_launch(void* const* d_in, const int* in_sizes, int n_in,
                              void* d_out, int out_size, void* d_ws, size_t ws_size,
                              hipStream_t stream) {
    const float* em   = (const float*)d_in[0];
    const int*   tags = (const int*)d_in[1];
    const float* T    = (const float*)d_in[2];
    float* out = (float*)d_out;
    crf_fwd<<<dim3(B_N), dim3(TG), 0, stream>>>(em, tags, T, out);
}

// Round 5
// 365.820 us; speedup vs baseline: 1.1692x; 1.0165x over previous
//
#include <hip/hip_runtime.h>

// CRF log-likelihood, B=1024, S=512, TAGSET=64, NUM_TAGS=66.
// One wave per batch element; lane j holds alpha_j and expT[:,j].
// R5: pin the 64 expT values into arch VGPRs INSIDE the loop (empty asm
// "+v" each iteration). R1-R4 evidence: VGPR_Count=44 with no scratch/global
// traffic => RA parked the column in AGPRs; each use paid v_accvgpr_read +
// hazard (~550 cy/step of stall at 1 wave/SIMD, zero TLP). In-loop pins make
// AGPR residency strictly more expensive than VGPR residency, forcing the
// allocator to keep the column in VGPRs. Empty asm emits no instructions.

#define B_N   1024
#define S_N   512
#define TG    64
#define NT    66
#define STARTT 64
#define STOPT  65
#define PD    4     // emission prefetch depth
#define TPD   3     // tag prefetch depth

__device__ __forceinline__ float bcastf(float v, int l) {
    return __uint_as_float(__builtin_amdgcn_readlane(__float_as_uint(v), l));
}

#define PIN(x) asm volatile("" : "+v"(x))

// 16 groups of 4 explicit indices.
#define GROUPS(M) \
  M(0,1,2,3)     M(4,5,6,7)     M(8,9,10,11)   M(12,13,14,15) \
  M(16,17,18,19) M(20,21,22,23) M(24,25,26,27) M(28,29,30,31) \
  M(32,33,34,35) M(36,37,38,39) M(40,41,42,43) M(44,45,46,47) \
  M(48,49,50,51) M(52,53,54,55) M(56,57,58,59) M(60,61,62,63)

__global__ __launch_bounds__(64, 1) void crf_fwd(
    const float* __restrict__ em,    // [B,S,64]
    const int*   __restrict__ tags,  // [B,S]
    const float* __restrict__ T,     // [66,66]
    float*       __restrict__ out)   // [B]
{
    const int b    = blockIdx.x;
    const int lane = threadIdx.x;  // 0..63

    __shared__ int s_tags[S_N];

    // Stage this batch's tags into LDS (coalesced).
    const int* tb = tags + b * S_N;
#pragma unroll
    for (int k = 0; k < S_N / TG; ++k)
        s_tags[k * TG + lane] = tb[k * TG + lane];

    // expT column for this lane: e{i} = exp(T[i][lane]), i = 0..63.
    const float* Tl = T + lane;
#define INITG(a,b_,c_,d_) \
    float e##a  = __expf(Tl[a  * NT]); \
    float e##b_ = __expf(Tl[b_ * NT]); \
    float e##c_ = __expf(Tl[c_ * NT]); \
    float e##d_ = __expf(Tl[d_ * NT]);
    GROUPS(INITG)
#undef INITG

    const float Tstart = T[STARTT * NT + lane];   // T[START, lane]
    const float Tend   = T[lane * NT + STOPT];    // T[lane, STOP]

    const float* emb = em + (size_t)b * (S_N * TG);
    float alpha = emb[lane] + Tstart;             // log_alpha0

    __syncthreads();

    // Register prefetch pipelines (scalars only).
    float em_pre0 = emb[1 * TG + lane];
    float em_pre1 = emb[2 * TG + lane];
    float em_pre2 = emb[3 * TG + lane];
    float em_pre3 = emb[4 * TG + lane];
    int tag_pre0 = s_tags[1];
    int tag_pre1 = s_tags[2];
    int tag_pre2 = s_tags[3];

    for (int t = 1; t < S_N; ++t) {
        // IN-LOOP pins: force arch-VGPR residency for the expT column every
        // iteration (prevents RA from parking the column in AGPRs and paying
        // v_accvgpr_read + hazard per use). Emits no instructions.
#define PING(a,b_,c_,d_) PIN(e##a); PIN(e##b_); PIN(e##c_); PIN(e##d_);
        GROUPS(PING)
#undef PING

        const float em_cur = em_pre0;
        em_pre0 = em_pre1; em_pre1 = em_pre2; em_pre2 = em_pre3;
        int tp = t + PD; tp = (tp < S_N - 1) ? tp : (S_N - 1);
        em_pre3 = emb[tp * TG + lane];

        const int tag = __builtin_amdgcn_readfirstlane(tag_pre0);
        tag_pre0 = tag_pre1; tag_pre1 = tag_pre2;
        int tn = t + TPD; tn = (tn < S_N - 1) ? tn : (S_N - 1);
        tag_pre2 = s_tags[tn];

        if (tag != 0) {
            // Wave-uniform shift: exact for logsumexp; lane0's alpha keeps
            // |alpha - m| <= ~12 (emission spread bound).
            const float m = bcastf(alpha, 0);
            const float E = __expf(alpha - m);

            // s_j = sum_i E_i * expT[i][j]; E_i broadcast via v_readlane
            // (immediate lane -> SGPR feeding v_fmac). 4 chains for ILP.
            float s0 = 0.f, s1 = 0.f, s2 = 0.f, s3 = 0.f;
#define FMAG(a,b_,c_,d_) \
            s0 = fmaf(bcastf(E, a ), e##a , s0); \
            s1 = fmaf(bcastf(E, b_), e##b_, s1); \
            s2 = fmaf(bcastf(E, c_), e##c_, s2); \
            s3 = fmaf(bcastf(E, d_), e##d_, s3);
            GROUPS(FMAG)
#undef FMAG
            const float ssum = (s0 + s1) + (s2 + s3);
            alpha = __logf(ssum) + m + em_cur + Tend;
        } else {
            alpha += Tend;
        }
    }

    // log_z = logsumexp_j(alpha) — once; butterfly cost irrelevant here.
    float mz = alpha;
#pragma unroll
    for (int d = 1; d < TG; d <<= 1)
        mz = fmaxf(mz, __shfl_xor(mz, d));
    float ez = __expf(alpha - mz);
#pragma unroll
    for (int d = 1; d < TG; d <<= 1)
        ez += __shfl_xor(ez, d);
    const float log_z = __logf(ez) + mz;

    // Numerator: gold-path score. 8 timesteps per lane.
    float num = 0.0f;
    int   cnt = 0;
#pragma unroll
    for (int k = 0; k < S_N / TG; ++k) {
        const int t   = k * TG + lane;
        const int tag = s_tags[t];
        const int mt  = (tag != 0) ? 1 : 0;
        cnt += mt;
        const float emg = emb[t * TG + tag];
        if (t == 0) {
            num += T[STARTT * NT + tag] + emg * (float)mt;
        } else {
            const int prev = s_tags[t - 1];
            num += (emg + T[prev * NT + tag]) * (float)mt;
        }
    }
#pragma unroll
    for (int d = 1; d < TG; d <<= 1) {
        num += __shfl_xor(num, d);
        cnt += __shfl_xor(cnt, d);
    }
    int last_idx = cnt - 1;
    if (last_idx < 0) last_idx = 0;
    const int last_tag = s_tags[last_idx];
    num += T[last_tag * NT + STOPT];

    if (lane == 0) out[b] = num - log_z;
}

extern "C" void kernel_launch(void* const* d_in, const int* in_sizes, int n_in,
                              void* d_out, int out_size, void* d_ws, size_t ws_size,
                              hipStream_t stream) {
    const float* em   = (const float*)d_in[0];
    const int*   tags = (const int*)d_in[1];
    const float* T    = (const float*)d_in[2];
    float* out = (float*)d_out;
    crf_fwd<<<dim3(B_N), dim3(TG), 0, stream>>>(em, tags, T, out);
}